// Round 1
// baseline (328.526 us; speedup 1.0000x reference)
//
#include <hip/hip_runtime.h>
#include <hip/hip_bf16.h>

#define IN_D 16
#define OUT_D 273   // 1 + 16 + 256

// One wave (64 lanes) per input row.
// Row layout of output: [t0 (1), t1 (16), x2 (256)].
// Quadratic element q = i*16 + j sits at p = 17 + q. With p = 17 + s*64 + lane
// (s = 0..3): i = 4*s + (lane>>4), j = lane & 15. All x-values fetched via
// __shfl from lanes 0..15 (no runtime-indexed register array -> no scratch).
__global__ __launch_bounds__(256) void TaylorExp_kernel(
    const float* __restrict__ x, float* __restrict__ out, int nrows) {
    const int lane = threadIdx.x & 63;
    const int waves_per_block = blockDim.x >> 6;
    int wave = blockIdx.x * waves_per_block + (threadIdx.x >> 6);
    const int wave_stride = gridDim.x * waves_per_block;

    const float t1_scale = 0.5f;                  // 1 / 16^(1/4)
    const float q_scale  = 0.17677669529663689f;  // 1 / (sqrt(2) * sqrt(16))

    const int hi = lane >> 4;

    for (int row = wave; row < nrows; row += wave_stride) {
        float v = 0.0f;
        if (lane < IN_D) v = x[(size_t)row * IN_D + lane];

        // j-operand: x[lane & 15]; i-operands for the 4 quad stores.
        float xj  = __shfl(v, lane & 15, 64);
        float xi0 = __shfl(v,      hi, 64);
        float xi1 = __shfl(v,  4 + hi, 64);
        float xi2 = __shfl(v,  8 + hi, 64);
        float xi3 = __shfl(v, 12 + hi, 64);

        float* o = out + (size_t)row * OUT_D;
        if (lane == 0)   o[0] = 1.0f;
        if (lane < IN_D) o[1 + lane] = v * t1_scale;
        o[17 +   0 + lane] = xi0 * xj * q_scale;
        o[17 +  64 + lane] = xi1 * xj * q_scale;
        o[17 + 128 + lane] = xi2 * xj * q_scale;
        o[17 + 192 + lane] = xi3 * xj * q_scale;
    }
}

extern "C" void kernel_launch(void* const* d_in, const int* in_sizes, int n_in,
                              void* d_out, int out_size, void* d_ws, size_t ws_size,
                              hipStream_t stream) {
    const float* x = (const float*)d_in[0];
    float* out = (float*)d_out;
    const int nrows = in_sizes[0] / IN_D;  // 262144

    const int block = 256;
    const int waves_per_block = block / 64;
    // Memory-bound: cap grid and grid-stride (Guideline 11).
    int total_waves_needed = nrows;
    int blocks_needed = (total_waves_needed + waves_per_block - 1) / waves_per_block;
    int grid = blocks_needed < 2048 ? blocks_needed : 2048;

    TaylorExp_kernel<<<grid, block, 0, stream>>>(x, out, nrows);
}

// Round 2
// 312.088 us; speedup vs baseline: 1.0527x; 1.0527x over previous
//
#include <hip/hip_runtime.h>
#include <hip/hip_bf16.h>

#define IN_D 16
#define ROW_F 273                    // floats per output row (1 + 16 + 256)
#define GROUP_ROWS 4
#define GROUP_F (ROW_F * GROUP_ROWS) // 1092 floats per 4-row group
#define GROUP_V4 (GROUP_F / 4)       // 273 float4 per group (4368 B, 16B-aligned)

// One wave per 4-row group. Wave loads all 64 input floats of its 4 rows
// (one coalesced 256B load; lane l holds x[4g + l/16][l%16]), then writes the
// group's 1092 output floats as 273 aligned float4 stores (5 iterations).
// Operand fetch via __shfl (ds_bpermute) from the wave's register file.
__global__ __launch_bounds__(256) void TaylorExp_kernel(
    const float* __restrict__ x, float4* __restrict__ out, int ngroups) {
    const int lane = threadIdx.x & 63;
    const int wid = blockIdx.x * (blockDim.x >> 6) + (threadIdx.x >> 6);
    const int wstride = gridDim.x * (blockDim.x >> 6);

    const float QS = 0.17677669529663689f;  // 1/(sqrt(2)*sqrt(16))

    for (int g = wid; g < ngroups; g += wstride) {
        // 64 contiguous input floats for rows 4g..4g+3.
        float v = x[(size_t)g * 64 + lane];
        float4* obase = out + (size_t)g * GROUP_V4;

        #pragma unroll
        for (int it = 0; it < 5; ++it) {
            int m = it * 64 + lane;                      // float4 index in group
            int mm = m < GROUP_V4 ? m : GROUP_V4 - 1;    // clamp (shuffles stay uniform)
            int f0 = mm * 4;                             // flat float index in group
            float4 o;
            float* op = &o.x;
            #pragma unroll
            for (int k = 0; k < 4; ++k) {
                int f = f0 + k;
                // r = f / 273 for f in [0, 1092) via compare tree
                int r = (f >= 2 * ROW_F) ? ((f >= 3 * ROW_F) ? 3 : 2)
                                         : ((f >= ROW_F) ? 1 : 0);
                int c = f - r * ROW_F;
                int q = c - 17;
                bool quad = (q >= 0);
                int ia = quad ? (q >> 4) : (c - 1);
                if (ia < 0) ia = 0;                      // c==0 case, value unused
                int ib = quad ? (q & 15) : 0;
                float a = __shfl(v, r * 16 + ia, 64);
                float b = __shfl(v, r * 16 + ib, 64);
                float val = quad ? a * b * QS : a * 0.5f;
                if (c == 0) val = 1.0f;
                op[k] = val;
            }
            if (m < GROUP_V4) obase[m] = o;
        }
    }
}

extern "C" void kernel_launch(void* const* d_in, const int* in_sizes, int n_in,
                              void* d_out, int out_size, void* d_ws, size_t ws_size,
                              hipStream_t stream) {
    const float* x = (const float*)d_in[0];
    float4* out = (float4*)d_out;
    const int nrows = in_sizes[0] / IN_D;    // 262144
    const int ngroups = nrows / GROUP_ROWS;  // 65536 (nrows divisible by 4)

    const int block = 256;                   // 4 waves/block
    const int waves_per_block = block / 64;
    int blocks_needed = (ngroups + waves_per_block - 1) / waves_per_block;
    int grid = blocks_needed < 2048 ? blocks_needed : 2048;  // grid-stride the rest

    TaylorExp_kernel<<<grid, block, 0, stream>>>(x, out, ngroups);
}